// Round 5
// baseline (488.776 us; speedup 1.0000x reference)
//
#include <hip/hip_runtime.h>
#include <hip/hip_bf16.h>

#define NN 50000
#define NE 500000
#define HID 128
#define LAYERS 3
#define RELS 8
#define BASES 30
#define GRAPHS 16
#define CLASSES 8
#define EPSV 1e-5f
#define NOUT (HID * (RELS + 1))   // 1152
#define NSEG (NN * RELS)          // 400000 (dst,rel) segments
#define SCAN_CHUNK 1024
#define SCAN_NBLK2 ((NSEG + SCAN_CHUNK - 1) / SCAN_CHUNK)   // 391
#define PCHUNK 128
#define DTILE 64
#define NDBLK ((NN + DTILE - 1) / DTILE)                     // 782

typedef __attribute__((ext_vector_type(8))) short short8;   // 8 bf16 (4 VGPRs)
typedef __attribute__((ext_vector_type(4))) float f32x4;    // MFMA accumulator

__device__ __forceinline__ float bf2f(unsigned short u) {
    union { unsigned int i; float f; } x; x.i = ((unsigned int)u) << 16; return x.f;
}
__device__ __forceinline__ unsigned short f2bf(float f) {
    __hip_bfloat16 b = __float2bfloat16(f);
    return *(unsigned short*)&b;
}
__device__ __forceinline__ float ubf_lo(unsigned w) {
    union { unsigned i; float f; } t; t.i = w << 16; return t.f;
}
__device__ __forceinline__ float ubf_hi(unsigned w) {
    union { unsigned i; float f; } t; t.i = w & 0xFFFF0000u; return t.f;
}
// storage permutation: feature f lives at in-row position perm(f).
__device__ __forceinline__ int permf(int f) {
    return (f & 64) | ((f & 15) << 2) | ((f >> 4) & 3);
}
__device__ __forceinline__ int ipermf(int q) {
    return (q & 64) | ((q & 3) << 4) | ((q >> 2) & 15);
}
// async global->LDS, 16B per lane; LDS dest = wave-uniform base + lane*16
__device__ __forceinline__ void gload16(const void* g, void* l) {
    __builtin_amdgcn_global_load_lds(
        (const __attribute__((address_space(1))) unsigned int*)g,
        (__attribute__((address_space(3))) unsigned int*)l, 16, 0, 0);
}

// ---------------- wT: [L][1152 n][128 k] bf16, k stored at perm(k)
__global__ __launch_bounds__(256) void build_wcat(const float* __restrict__ basis,
                                                  const float* __restrict__ comp,
                                                  const float* __restrict__ root,
                                                  unsigned short* __restrict__ wT) {
    int bid = blockIdx.x;
    int l = bid >> 6;               // 0..2
    int k0 = (bid & 63) << 1;       // 0,2,..,126
    __shared__ float cl[RELS * BASES];   // 240
    int tid = threadIdx.x;
    if (tid < RELS * BASES) cl[tid] = comp[l * RELS * BASES + tid];
    __syncthreads();
    int j = tid & 127;
    int k = k0 + (tid >> 7);
    int pk = permf(k);
    const float* bp = basis + ((size_t)l * BASES * HID + k) * HID + j;
    float acc[RELS];
#pragma unroll
    for (int r = 0; r < RELS; ++r) acc[r] = 0.f;
    for (int b = 0; b < BASES; ++b) {
        float v = bp[(size_t)b * HID * HID];
#pragma unroll
        for (int r = 0; r < RELS; ++r) acc[r] += cl[r * BASES + b] * v;
    }
    unsigned short* wl = wT + (size_t)l * NOUT * HID;
#pragma unroll
    for (int r = 0; r < RELS; ++r)
        wl[(size_t)((1 + r) * HID + j) * HID + pk] = f2bf(acc[r]);
    wl[(size_t)j * HID + pk] = f2bf(root[((size_t)l * HID + k) * HID + j]);
}

// ---------------- BN1 (eval mode) -> bf16, permuted feature storage
__global__ void bn1_kernel(const float* __restrict__ x, const float* __restrict__ gamma,
                           const float* __restrict__ beta, const float* __restrict__ mean,
                           const float* __restrict__ var, unsigned short* __restrict__ habf) {
    int idx = blockIdx.x * blockDim.x + threadIdx.x;
    if (idx >= NN * HID) return;
    int q = idx & (HID - 1);
    int n = idx >> 7;
    int f = ipermf(q);
    habf[idx] = f2bf((x[(n << 7) + f] - mean[f]) * rsqrtf(var[f] + EPSV) * gamma[f] + beta[f]);
}

// ---------------- degree count per (dst, rel) segment
__global__ void deg_kernel(const int* __restrict__ ei, const int* __restrict__ ea,
                           float* __restrict__ deg) {
    int e = blockIdx.x * blockDim.x + threadIdx.x;
    if (e >= NE) return;
    int dst = ei[NE + e];
    atomicAdd(&deg[(size_t)dst * RELS + ea[e]], 1.0f);
}

// ---------------- fused: deg->invdeg (in place) + partial scan over 400K segments
__global__ __launch_bounds__(256) void scan_partial(float* __restrict__ deg,
                                                    int* __restrict__ rowptr,
                                                    int* __restrict__ bsum) {
    __shared__ int ssc[256];
    int t = threadIdx.x;
    int base = blockIdx.x * SCAN_CHUNK + t * 4;
    int v[4];
#pragma unroll
    for (int j = 0; j < 4; ++j) {
        int seg = base + j;
        if (seg < NSEG) {
            float d = deg[seg];
            v[j] = (int)(d + 0.5f);
            deg[seg] = 1.0f / fmaxf(d, 1.0f);
        } else v[j] = 0;
    }
    int tsum = v[0] + v[1] + v[2] + v[3];
    ssc[t] = tsum;
    __syncthreads();
    for (int ofs = 1; ofs < 256; ofs <<= 1) {
        int add = (t >= ofs) ? ssc[t - ofs] : 0;
        __syncthreads();
        ssc[t] += add;
        __syncthreads();
    }
    int excl = ssc[t] - tsum;
    int e = 0;
#pragma unroll
    for (int j = 0; j < 4; ++j) {
        if (base + j < NSEG) rowptr[base + j] = excl + e;
        e += v[j];
    }
    if (t == 255) bsum[blockIdx.x] = ssc[255];
}

// parallel exclusive scan of the 391 block sums (one 512-thread block)
__global__ __launch_bounds__(512) void scan_bsum(int* __restrict__ bsum) {
    __shared__ int s[512];
    int t = threadIdx.x;
    int v = (t < SCAN_NBLK2) ? bsum[t] : 0;
    s[t] = v;
    __syncthreads();
    for (int o = 1; o < 512; o <<= 1) {
        int a = (t >= o) ? s[t - o] : 0;
        __syncthreads();
        s[t] += a;
        __syncthreads();
    }
    if (t < SCAN_NBLK2) bsum[t] = s[t] - v;
}

__global__ __launch_bounds__(256) void scan_add(int* __restrict__ rowptr,
                                                const int* __restrict__ bsum) {
    int i = blockIdx.x * blockDim.x + threadIdx.x;
    if (i < NSEG) rowptr[i] += bsum[i >> 10];
    if (i == 0) rowptr[NSEG] = NE;
}

// ---------------- fill CSR keyed by (dst,rel): epk2[slot] = src
__global__ void fill_kernel(const int* __restrict__ ei, const int* __restrict__ ea,
                            const int* __restrict__ rowptr,
                            int* __restrict__ fillcnt, int* __restrict__ epk) {
    int e = blockIdx.x * blockDim.x + threadIdx.x;
    if (e >= NE) return;
    int src = ei[e];
    int seg = ei[NE + e] * RELS + ea[e];
    int pos = atomicAdd(&fillcnt[seg], 1);
    epk[rowptr[seg] + pos] = src;
}

// ---------------- fused RGCN layer: aggregate-then-transform.
// Per block: 64 dst rows x 128 out. 9 K-panels (root + 8 relations), effective K=1152.
// Panel 0: A = hin[dst] staged via global_load_lds (both-sides XOR swizzle).
// Panels 1..8: A = invdeg * sum_{src in N_r(dst)} hin[src], gathered in f32 registers
//   (4 threads/dst, 32 feats each), written bf16 to As with the same XOR swizzle.
// All storage-space positional; epilogue adds bias, ReLU, perm-packed bf16 stores.
__global__ __launch_bounds__(256) void rgcn_layer(const unsigned short* __restrict__ hin,
                                                  const unsigned short* __restrict__ wTl,
                                                  const float* __restrict__ bias,
                                                  const int* __restrict__ rp2,
                                                  const int* __restrict__ epk2,
                                                  const float* __restrict__ invdeg,
                                                  unsigned short* __restrict__ hout) {
    __shared__ __align__(16) unsigned short As[DTILE * HID];   // 16 KB
    __shared__ __align__(16) unsigned short Bs[128 * HID];     // 32 KB
    int row0 = blockIdx.x * DTILE;
    int tid = threadIdx.x;
    int wave = tid >> 6, lane = tid & 63;
    int quad = lane >> 4, l16 = lane & 15;
    int wn = wave * 32;            // this wave's 32 output cols
    int ld = tid >> 2, tq = tid & 3;   // gather identity: dst-local row, feat quarter
    int dst = row0 + ld;

    f32x4 acc[4][2];
#pragma unroll
    for (int i = 0; i < 4; ++i)
#pragma unroll
        for (int j = 0; j < 2; ++j) acc[i][j] = (f32x4){0.f, 0.f, 0.f, 0.f};

    auto mfma_panel = [&]() {
#pragma unroll
        for (int kc = 0; kc < 4; ++kc) {
            int ca = ((kc * 4 + quad) ^ (l16 & 7)) << 3;
            short8 a[4], b[2];
#pragma unroll
            for (int i = 0; i < 4; ++i) a[i] = *(const short8*)&As[(i * 16 + l16) * HID + ca];
#pragma unroll
            for (int j = 0; j < 2; ++j) b[j] = *(const short8*)&Bs[(wn + j * 16 + l16) * HID + ca];
#pragma unroll
            for (int i = 0; i < 4; ++i)
#pragma unroll
                for (int j = 0; j < 2; ++j)
                    acc[i][j] = __builtin_amdgcn_mfma_f32_16x16x32_bf16(a[i], b[j], acc[i][j], 0, 0, 0);
        }
    };

    // ---- prologue: stage root A-panel + B-panel 0
#pragma unroll
    for (int q = 0; q < 4; ++q) {
        int rb = (wave << 4) + (q << 2);
        int r = rb + (lane >> 4), c = lane & 15;
        int ga = row0 + r; if (ga > NN - 1) ga = NN - 1;   // clamp: tail rows never stored
        gload16(hin + (size_t)ga * HID + ((c ^ (r & 7)) << 3), &As[rb * HID]);
    }
#pragma unroll
    for (int q = 0; q < 8; ++q) {
        int rb = (wave << 5) + (q << 2);
        int r = rb + (lane >> 4), c = lane & 15;
        gload16(wTl + (size_t)r * HID + ((c ^ (r & 7)) << 3), &Bs[rb * HID]);
    }
    __syncthreads();
    mfma_panel();

    // ---- relation panels
    for (int p = 1; p <= RELS; ++p) {
        float ga[32];
#pragma unroll
        for (int i2 = 0; i2 < 32; ++i2) ga[i2] = 0.f;
        float s = 0.f;
        if (dst < NN) {
            int seg = dst * RELS + (p - 1);
            int beg = rp2[seg], end = rp2[seg + 1];
            s = invdeg[seg];
            for (int e = beg; e < end; ++e) {
                int src = epk2[e];
                const uint4* rp = (const uint4*)(hin + (size_t)src * HID + (tq << 5));
                uint4 q0 = rp[0], q1 = rp[1], q2 = rp[2], q3 = rp[3];
#pragma unroll
                for (int q4 = 0; q4 < 4; ++q4) {
                    uint4 u = (q4 == 0) ? q0 : (q4 == 1) ? q1 : (q4 == 2) ? q2 : q3;
                    ga[q4 * 8 + 0] += ubf_lo(u.x); ga[q4 * 8 + 1] += ubf_hi(u.x);
                    ga[q4 * 8 + 2] += ubf_lo(u.y); ga[q4 * 8 + 3] += ubf_hi(u.y);
                    ga[q4 * 8 + 4] += ubf_lo(u.z); ga[q4 * 8 + 5] += ubf_hi(u.z);
                    ga[q4 * 8 + 6] += ubf_lo(u.w); ga[q4 * 8 + 7] += ubf_hi(u.w);
                }
            }
        }
        __syncthreads();   // all waves done reading As/Bs of panel p-1
        // write aggregated A-panel (scaled, bf16, XOR-swizzled)
#pragma unroll
        for (int cc = 0; cc < 4; ++cc) {
            short8 v;
#pragma unroll
            for (int i2 = 0; i2 < 8; ++i2) v[i2] = (short)f2bf(ga[cc * 8 + i2] * s);
            int c = (tq << 2) + cc;
            *(short8*)&As[ld * HID + ((c ^ (ld & 7)) << 3)] = v;
        }
        // stage B-panel p
#pragma unroll
        for (int q = 0; q < 8; ++q) {
            int rb = (wave << 5) + (q << 2);
            int r = rb + (lane >> 4), c = lane & 15;
            gload16(wTl + (size_t)(p * 128 + r) * HID + ((c ^ (r & 7)) << 3), &Bs[rb * HID]);
        }
        __syncthreads();   // drains ds_writes + B-panel loads
        mfma_panel();
    }

    // ---- epilogue: bias + ReLU, perm-packed bf16 stores
    // out col c = wn + jj*16 + l16 -> storage pos = (c&64) + l16*4 + ((c>>4)&3)
    int pb = ((wave & 2) << 5) + (l16 << 2) + ((wave & 1) << 1);
    float b0 = bias[wn + l16], b1 = bias[wn + 16 + l16];
#pragma unroll
    for (int i = 0; i < 4; ++i)
#pragma unroll
        for (int reg = 0; reg < 4; ++reg) {
            int grow = row0 + i * 16 + quad * 4 + reg;
            if (grow >= NN) continue;
            unsigned u = (unsigned)f2bf(fmaxf(acc[i][0][reg] + b0, 0.f))
                       | ((unsigned)f2bf(fmaxf(acc[i][1][reg] + b1, 0.f)) << 16);
            *(unsigned*)(hout + (size_t)grow * HID + pb) = u;
        }
}

// ---------------- global mean pool: sorted-batch register accumulation (position-wise)
__global__ __launch_bounds__(256) void pool_kernel(const unsigned short* __restrict__ habf,
                                                   const int* __restrict__ batch,
                                                   float* __restrict__ psum,
                                                   float* __restrict__ pcnt) {
    int tid = threadIdx.x;
    int f = tid & 127;
    int sub = tid >> 7;
    int base = blockIdx.x * PCHUNK;
    float acc = 0.f, cnt = 0.f;
    int gcur = -1;
    for (int it = 0; it < PCHUNK / 2; ++it) {
        int node = base + it * 2 + sub;
        if (node >= NN) break;
        int g = batch[node];
        if (g != gcur) {
            if (gcur >= 0) {
                atomicAdd(&psum[gcur * HID + f], acc);
                if (f == 0) atomicAdd(&pcnt[gcur], cnt);
            }
            gcur = g; acc = 0.f; cnt = 0.f;
        }
        acc += bf2f(habf[(size_t)node * HID + f]);
        cnt += 1.f;
    }
    if (gcur >= 0) {
        atomicAdd(&psum[gcur * HID + f], acc);
        if (f == 0) atomicAdd(&pcnt[gcur], cnt);
    }
}

// ---------------- head (unpermutes psum)
__global__ void head_kernel(const float* __restrict__ psum, const float* __restrict__ pcnt,
                            const float* __restrict__ g2, const float* __restrict__ b2,
                            const float* __restrict__ m2, const float* __restrict__ v2,
                            const float* __restrict__ fc1w, const float* __restrict__ fc1b,
                            const float* __restrict__ fc2w, const float* __restrict__ fc2b,
                            float* __restrict__ out) {
    __shared__ float v[HID];
    __shared__ float u[HID];
    __shared__ float lg[CLASSES];
    int j = threadIdx.x;
    int pj = permf(j);
    float acc = 0.f;
    for (int g = 0; g < GRAPHS; ++g) {
        float val = psum[g * HID + pj] / fmaxf(pcnt[g], 1.0f);
        val = (val - m2[j]) * rsqrtf(v2[j] + EPSV) * g2[j] + b2[j];
        acc += val;
    }
    v[j] = fmaxf(acc / (float)GRAPHS, 0.f);
    __syncthreads();
    float s = fc1b[j];
    for (int k = 0; k < HID; ++k) s += v[k] * fc1w[k * HID + j];
    u[j] = fmaxf(s, 0.f);
    __syncthreads();
    if (j < CLASSES) {
        float t = fc2b[j];
        for (int k = 0; k < HID; ++k) t += u[k] * fc2w[k * CLASSES + j];
        lg[j] = t;
    }
    __syncthreads();
    if (j < CLASSES) {
        float mx = lg[0];
        for (int c = 1; c < CLASSES; ++c) mx = fmaxf(mx, lg[c]);
        float se = 0.f;
        for (int c = 0; c < CLASSES; ++c) se += expf(lg[c] - mx);
        out[j] = lg[j] - mx - logf(se);
    }
}

extern "C" void kernel_launch(void* const* d_in, const int* in_sizes, int n_in,
                              void* d_out, int out_size, void* d_ws, size_t ws_size,
                              hipStream_t stream) {
    const float* x     = (const float*)d_in[0];
    const int*   ei    = (const int*)d_in[1];
    const int*   ea    = (const int*)d_in[2];
    const int*   batch = (const int*)d_in[3];
    const float* bn1g  = (const float*)d_in[4];
    const float* bn1b  = (const float*)d_in[5];
    const float* bn1m  = (const float*)d_in[6];
    const float* bn1v  = (const float*)d_in[7];
    const float* basis = (const float*)d_in[8];
    const float* comp  = (const float*)d_in[9];
    const float* root  = (const float*)d_in[10];
    const float* bias  = (const float*)d_in[11];
    const float* bn2g  = (const float*)d_in[12];
    const float* bn2b  = (const float*)d_in[13];
    const float* bn2m  = (const float*)d_in[14];
    const float* bn2v  = (const float*)d_in[15];
    const float* fc1w  = (const float*)d_in[16];
    const float* fc1b  = (const float*)d_in[17];
    const float* fc2w  = (const float*)d_in[18];
    const float* fc2b  = (const float*)d_in[19];

    float* ws = (float*)d_ws;
    size_t off = 0;
    unsigned short* wT  = (unsigned short*)(ws + off); off += (size_t)LAYERS * NOUT * HID / 2;
    unsigned short* hb0 = (unsigned short*)(ws + off); off += (size_t)NN * HID / 2;
    unsigned short* hb1 = (unsigned short*)(ws + off); off += (size_t)NN * HID / 2;
    float* deg    = ws + off; off += (size_t)NSEG;
    float* psum   = ws + off; off += (size_t)GRAPHS * HID + GRAPHS;
    float* pcnt   = psum + GRAPHS * HID;
    int* rowptr2  = (int*)(ws + off); off += (size_t)NSEG + 1;
    int* fillcnt2 = (int*)(ws + off); off += (size_t)NSEG;
    int* bsum     = (int*)(ws + off); off += (size_t)SCAN_NBLK2;
    int* epk2     = (int*)(ws + off); off += (size_t)NE;
    if (ws_size < off * sizeof(float)) return;

    hipMemsetAsync(psum, 0, (GRAPHS * HID + GRAPHS) * sizeof(float), stream);
    hipMemsetAsync(deg, 0, (size_t)NSEG * sizeof(float), stream);
    hipMemsetAsync(fillcnt2, 0, (size_t)NSEG * sizeof(int), stream);

    build_wcat<<<LAYERS * 64, 256, 0, stream>>>(basis, comp, root, wT);
    bn1_kernel<<<(NN * HID + 255) / 256, 256, 0, stream>>>(x, bn1g, bn1b, bn1m, bn1v, hb0);

    deg_kernel<<<(NE + 255) / 256, 256, 0, stream>>>(ei, ea, deg);
    scan_partial<<<SCAN_NBLK2, 256, 0, stream>>>(deg, rowptr2, bsum);
    scan_bsum<<<1, 512, 0, stream>>>(bsum);
    scan_add<<<(NSEG + 255) / 256, 256, 0, stream>>>(rowptr2, bsum);
    fill_kernel<<<(NE + 255) / 256, 256, 0, stream>>>(ei, ea, rowptr2, fillcnt2, epk2);

    const unsigned short* hin = hb0;
    unsigned short* hout = hb1;
    for (int l = 0; l < LAYERS; ++l) {
        rgcn_layer<<<NDBLK, 256, 0, stream>>>(hin, wT + (size_t)l * NOUT * HID,
                                              bias + (size_t)l * HID, rowptr2, epk2, deg, hout);
        const unsigned short* t = hin; hin = hout; hout = (unsigned short*)t;
    }

    pool_kernel<<<(NN + PCHUNK - 1) / PCHUNK, 256, 0, stream>>>(hin, batch, psum, pcnt);
    head_kernel<<<1, 128, 0, stream>>>(psum, pcnt, bn2g, bn2b, bn2m, bn2v,
                                       fc1w, fc1b, fc2w, fc2b, (float*)d_out);
}

// Round 6
// 468.298 us; speedup vs baseline: 1.0437x; 1.0437x over previous
//
#include <hip/hip_runtime.h>
#include <hip/hip_bf16.h>

#define NN 50000
#define NE 500000
#define HID 128
#define LAYERS 3
#define RELS 8
#define BASES 30
#define GRAPHS 16
#define CLASSES 8
#define EPSV 1e-5f
#define NOUT (HID * (RELS + 1))   // 1152
#define NSEG (NN * RELS)          // 400000 (dst,rel) segments
#define SCAN_CHUNK 1024
#define SCAN_NBLK2 ((NSEG + SCAN_CHUNK - 1) / SCAN_CHUNK)   // 391
#define PCHUNK 128
#define DTILE 64
#define NDBLK ((NN + DTILE - 1) / DTILE)                     // 782
#define ECAP 28                   // prefetched edges per dst (u16); overflow -> epk2 fallback

typedef __attribute__((ext_vector_type(8))) short short8;   // 8 bf16 (4 VGPRs)
typedef __attribute__((ext_vector_type(4))) float f32x4;    // MFMA accumulator

__device__ __forceinline__ float bf2f(unsigned short u) {
    union { unsigned int i; float f; } x; x.i = ((unsigned int)u) << 16; return x.f;
}
__device__ __forceinline__ unsigned short f2bf(float f) {
    __hip_bfloat16 b = __float2bfloat16(f);
    return *(unsigned short*)&b;
}
__device__ __forceinline__ float ubf_lo(unsigned w) {
    union { unsigned i; float f; } t; t.i = w << 16; return t.f;
}
__device__ __forceinline__ float ubf_hi(unsigned w) {
    union { unsigned i; float f; } t; t.i = w & 0xFFFF0000u; return t.f;
}
// storage permutation: feature f lives at in-row position perm(f).
__device__ __forceinline__ int permf(int f) {
    return (f & 64) | ((f & 15) << 2) | ((f >> 4) & 3);
}
__device__ __forceinline__ int ipermf(int q) {
    return (q & 64) | ((q & 3) << 4) | ((q >> 2) & 15);
}
// async global->LDS, 16B per lane; LDS dest = wave-uniform base + lane*16
__device__ __forceinline__ void gload16(const void* g, void* l) {
    __builtin_amdgcn_global_load_lds(
        (const __attribute__((address_space(1))) unsigned int*)g,
        (__attribute__((address_space(3))) unsigned int*)l, 16, 0, 0);
}

// ---------------- wT: [L][1152 n][128 k] bf16, k stored at perm(k)
__global__ __launch_bounds__(256) void build_wcat(const float* __restrict__ basis,
                                                  const float* __restrict__ comp,
                                                  const float* __restrict__ root,
                                                  unsigned short* __restrict__ wT) {
    int bid = blockIdx.x;
    int l = bid >> 6;               // 0..2
    int k0 = (bid & 63) << 1;       // 0,2,..,126
    __shared__ float cl[RELS * BASES];   // 240
    int tid = threadIdx.x;
    if (tid < RELS * BASES) cl[tid] = comp[l * RELS * BASES + tid];
    __syncthreads();
    int j = tid & 127;
    int k = k0 + (tid >> 7);
    int pk = permf(k);
    const float* bp = basis + ((size_t)l * BASES * HID + k) * HID + j;
    float acc[RELS];
#pragma unroll
    for (int r = 0; r < RELS; ++r) acc[r] = 0.f;
    for (int b = 0; b < BASES; ++b) {
        float v = bp[(size_t)b * HID * HID];
#pragma unroll
        for (int r = 0; r < RELS; ++r) acc[r] += cl[r * BASES + b] * v;
    }
    unsigned short* wl = wT + (size_t)l * NOUT * HID;
#pragma unroll
    for (int r = 0; r < RELS; ++r)
        wl[(size_t)((1 + r) * HID + j) * HID + pk] = f2bf(acc[r]);
    wl[(size_t)j * HID + pk] = f2bf(root[((size_t)l * HID + k) * HID + j]);
}

// ---------------- BN1 (eval mode) -> bf16, permuted feature storage
__global__ void bn1_kernel(const float* __restrict__ x, const float* __restrict__ gamma,
                           const float* __restrict__ beta, const float* __restrict__ mean,
                           const float* __restrict__ var, unsigned short* __restrict__ habf) {
    int idx = blockIdx.x * blockDim.x + threadIdx.x;
    if (idx >= NN * HID) return;
    int q = idx & (HID - 1);
    int n = idx >> 7;
    int f = ipermf(q);
    habf[idx] = f2bf((x[(n << 7) + f] - mean[f]) * rsqrtf(var[f] + EPSV) * gamma[f] + beta[f]);
}

// ---------------- degree count per (dst, rel) segment
__global__ void deg_kernel(const int* __restrict__ ei, const int* __restrict__ ea,
                           float* __restrict__ deg) {
    int e = blockIdx.x * blockDim.x + threadIdx.x;
    if (e >= NE) return;
    int dst = ei[NE + e];
    atomicAdd(&deg[(size_t)dst * RELS + ea[e]], 1.0f);
}

// ---------------- fused: deg->invdeg (in place) + partial scan over 400K segments
__global__ __launch_bounds__(256) void scan_partial(float* __restrict__ deg,
                                                    int* __restrict__ rowptr,
                                                    int* __restrict__ bsum) {
    __shared__ int ssc[256];
    int t = threadIdx.x;
    int base = blockIdx.x * SCAN_CHUNK + t * 4;
    int v[4];
#pragma unroll
    for (int j = 0; j < 4; ++j) {
        int seg = base + j;
        if (seg < NSEG) {
            float d = deg[seg];
            v[j] = (int)(d + 0.5f);
            deg[seg] = 1.0f / fmaxf(d, 1.0f);
        } else v[j] = 0;
    }
    int tsum = v[0] + v[1] + v[2] + v[3];
    ssc[t] = tsum;
    __syncthreads();
    for (int ofs = 1; ofs < 256; ofs <<= 1) {
        int add = (t >= ofs) ? ssc[t - ofs] : 0;
        __syncthreads();
        ssc[t] += add;
        __syncthreads();
    }
    int excl = ssc[t] - tsum;
    int e = 0;
#pragma unroll
    for (int j = 0; j < 4; ++j) {
        if (base + j < NSEG) rowptr[base + j] = excl + e;
        e += v[j];
    }
    if (t == 255) bsum[blockIdx.x] = ssc[255];
}

// parallel exclusive scan of the 391 block sums (one 512-thread block)
__global__ __launch_bounds__(512) void scan_bsum(int* __restrict__ bsum) {
    __shared__ int s[512];
    int t = threadIdx.x;
    int v = (t < SCAN_NBLK2) ? bsum[t] : 0;
    s[t] = v;
    __syncthreads();
    for (int o = 1; o < 512; o <<= 1) {
        int a = (t >= o) ? s[t - o] : 0;
        __syncthreads();
        s[t] += a;
        __syncthreads();
    }
    if (t < SCAN_NBLK2) bsum[t] = s[t] - v;
}

__global__ __launch_bounds__(256) void scan_add(int* __restrict__ rowptr,
                                                const int* __restrict__ bsum) {
    int i = blockIdx.x * blockDim.x + threadIdx.x;
    if (i < NSEG) rowptr[i] += bsum[i >> 10];
    if (i == 0) rowptr[NSEG] = NE;
}

// ---------------- fill CSR keyed by (dst,rel): epk2[slot] = src
__global__ void fill_kernel(const int* __restrict__ ei, const int* __restrict__ ea,
                            const int* __restrict__ rowptr,
                            int* __restrict__ fillcnt, int* __restrict__ epk) {
    int e = blockIdx.x * blockDim.x + threadIdx.x;
    if (e >= NE) return;
    int src = ei[e];
    int seg = ei[NE + e] * RELS + ea[e];
    int pos = atomicAdd(&fillcnt[seg], 1);
    epk[rowptr[seg] + pos] = src;
}

// ---------------- fused RGCN layer: aggregate-then-transform, latency-fixed.
// Block start: prefetch phase loads all CSR metadata (boundaries u16, srcs u16, base)
// into LDS in parallel -> per-panel gather is {LDS u16 read -> hin load}, no chain.
// Panels / MFMA / swizzle / epilogue identical to the R5-verified kernel.
__global__ __launch_bounds__(256) void rgcn_layer(const unsigned short* __restrict__ hin,
                                                  const unsigned short* __restrict__ wTl,
                                                  const float* __restrict__ bias,
                                                  const int* __restrict__ rp2,
                                                  const int* __restrict__ epk2,
                                                  const float* __restrict__ invdeg,
                                                  unsigned short* __restrict__ hout) {
    __shared__ __align__(16) unsigned short As[DTILE * HID];   // 16 KB
    __shared__ __align__(16) unsigned short Bs[128 * HID];     // 32 KB
    __shared__ unsigned short bnd_l[DTILE * 9];                // local seg boundaries
    __shared__ unsigned short src_l[DTILE * ECAP];             // prefetched srcs (u16)
    __shared__ int base_l[DTILE];                              // abs CSR base per dst
    int row0 = blockIdx.x * DTILE;
    int tid = threadIdx.x;
    int wave = tid >> 6, lane = tid & 63;
    int quad = lane >> 4, l16 = lane & 15;
    int wn = wave * 32;            // this wave's 32 output cols
    int ld = tid >> 2, tq = tid & 3;   // gather identity: dst-local row, feat quarter
    int dst = row0 + ld;
    bool ok = dst < NN;

    f32x4 acc[4][2];
#pragma unroll
    for (int i = 0; i < 4; ++i)
#pragma unroll
        for (int j = 0; j < 2; ++j) acc[i][j] = (f32x4){0.f, 0.f, 0.f, 0.f};

    auto mfma_panel = [&]() {
#pragma unroll
        for (int kc = 0; kc < 4; ++kc) {
            int ca = ((kc * 4 + quad) ^ (l16 & 7)) << 3;
            short8 a[4], b[2];
#pragma unroll
            for (int i = 0; i < 4; ++i) a[i] = *(const short8*)&As[(i * 16 + l16) * HID + ca];
#pragma unroll
            for (int j = 0; j < 2; ++j) b[j] = *(const short8*)&Bs[(wn + j * 16 + l16) * HID + ca];
#pragma unroll
            for (int i = 0; i < 4; ++i)
#pragma unroll
                for (int j = 0; j < 2; ++j)
                    acc[i][j] = __builtin_amdgcn_mfma_f32_16x16x32_bf16(a[i], b[j], acc[i][j], 0, 0, 0);
        }
    };

    // ---- prefetch phase: CSR metadata -> LDS (parallel, breaks the load chain)
    {
        int base = ok ? rp2[dst * RELS] : 0;
        int endt = ok ? rp2[dst * RELS + 8] : 0;
        int b0 = ok ? rp2[dst * RELS + tq] : 0;
        int b1 = ok ? rp2[dst * RELS + 4 + tq] : 0;
        bnd_l[ld * 9 + tq] = (unsigned short)(b0 - base);
        bnd_l[ld * 9 + 4 + tq] = (unsigned short)(b1 - base);
        if (tq == 0) {
            bnd_l[ld * 9 + 8] = (unsigned short)(endt - base);
            base_l[ld] = base;
        }
        int degt = endt - base;
        int lim = degt < ECAP ? degt : ECAP;
        for (int e = tq; e < lim; e += 4)
            src_l[ld * ECAP + e] = (unsigned short)epk2[base + e];
    }

    // ---- stage root A-panel + B-panel 0 (async, drains at first barrier)
#pragma unroll
    for (int q = 0; q < 4; ++q) {
        int rb = (wave << 4) + (q << 2);
        int r = rb + (lane >> 4), c = lane & 15;
        int ga = row0 + r; if (ga > NN - 1) ga = NN - 1;   // clamp: tail rows never stored
        gload16(hin + (size_t)ga * HID + ((c ^ (r & 7)) << 3), &As[rb * HID]);
    }
#pragma unroll
    for (int q = 0; q < 8; ++q) {
        int rb = (wave << 5) + (q << 2);
        int r = rb + (lane >> 4), c = lane & 15;
        gload16(wTl + (size_t)r * HID + ((c ^ (r & 7)) << 3), &Bs[rb * HID]);
    }
    __syncthreads();
    mfma_panel();

    // ---- relation panels
    for (int p = 1; p <= RELS; ++p) {
        float ga[32];
#pragma unroll
        for (int i2 = 0; i2 < 32; ++i2) ga[i2] = 0.f;
        float s = 0.f;
        if (ok) {
            int seg = dst * RELS + (p - 1);
            s = invdeg[seg];                         // issued early, used after gather
            int bl = bnd_l[ld * 9 + (p - 1)];
            int el = bnd_l[ld * 9 + p];
            int e = bl;
            for (; e + 2 <= el; e += 2) {
                int s0 = (e < ECAP) ? (int)src_l[ld * ECAP + e] : epk2[base_l[ld] + e];
                int s1 = (e + 1 < ECAP) ? (int)src_l[ld * ECAP + e + 1] : epk2[base_l[ld] + e + 1];
                const uint4* ra = (const uint4*)(hin + (size_t)s0 * HID + (tq << 5));
                const uint4* rb = (const uint4*)(hin + (size_t)s1 * HID + (tq << 5));
                uint4 a0 = ra[0], a1 = ra[1], a2 = ra[2], a3 = ra[3];
                uint4 b0 = rb[0], b1 = rb[1], b2 = rb[2], b3 = rb[3];
#pragma unroll
                for (int q4 = 0; q4 < 4; ++q4) {
                    uint4 u = (q4 == 0) ? a0 : (q4 == 1) ? a1 : (q4 == 2) ? a2 : a3;
                    uint4 v = (q4 == 0) ? b0 : (q4 == 1) ? b1 : (q4 == 2) ? b2 : b3;
                    ga[q4 * 8 + 0] += ubf_lo(u.x) + ubf_lo(v.x); ga[q4 * 8 + 1] += ubf_hi(u.x) + ubf_hi(v.x);
                    ga[q4 * 8 + 2] += ubf_lo(u.y) + ubf_lo(v.y); ga[q4 * 8 + 3] += ubf_hi(u.y) + ubf_hi(v.y);
                    ga[q4 * 8 + 4] += ubf_lo(u.z) + ubf_lo(v.z); ga[q4 * 8 + 5] += ubf_hi(u.z) + ubf_hi(v.z);
                    ga[q4 * 8 + 6] += ubf_lo(u.w) + ubf_lo(v.w); ga[q4 * 8 + 7] += ubf_hi(u.w) + ubf_hi(v.w);
                }
            }
            if (e < el) {
                int s0 = (e < ECAP) ? (int)src_l[ld * ECAP + e] : epk2[base_l[ld] + e];
                const uint4* ra = (const uint4*)(hin + (size_t)s0 * HID + (tq << 5));
                uint4 a0 = ra[0], a1 = ra[1], a2 = ra[2], a3 = ra[3];
#pragma unroll
                for (int q4 = 0; q4 < 4; ++q4) {
                    uint4 u = (q4 == 0) ? a0 : (q4 == 1) ? a1 : (q4 == 2) ? a2 : a3;
                    ga[q4 * 8 + 0] += ubf_lo(u.x); ga[q4 * 8 + 1] += ubf_hi(u.x);
                    ga[q4 * 8 + 2] += ubf_lo(u.y); ga[q4 * 8 + 3] += ubf_hi(u.y);
                    ga[q4 * 8 + 4] += ubf_lo(u.z); ga[q4 * 8 + 5] += ubf_hi(u.z);
                    ga[q4 * 8 + 6] += ubf_lo(u.w); ga[q4 * 8 + 7] += ubf_hi(u.w);
                }
            }
        }
        __syncthreads();   // all waves done reading As/Bs of panel p-1
        // write aggregated A-panel (scaled, bf16, XOR-swizzled)
#pragma unroll
        for (int cc = 0; cc < 4; ++cc) {
            short8 v;
#pragma unroll
            for (int i2 = 0; i2 < 8; ++i2) v[i2] = (short)f2bf(ga[cc * 8 + i2] * s);
            int c = (tq << 2) + cc;
            *(short8*)&As[ld * HID + ((c ^ (ld & 7)) << 3)] = v;
        }
        // stage B-panel p
#pragma unroll
        for (int q = 0; q < 8; ++q) {
            int rb = (wave << 5) + (q << 2);
            int r = rb + (lane >> 4), c = lane & 15;
            gload16(wTl + (size_t)(p * 128 + r) * HID + ((c ^ (r & 7)) << 3), &Bs[rb * HID]);
        }
        __syncthreads();   // drains ds_writes + B-panel loads
        mfma_panel();
    }

    // ---- epilogue: bias + ReLU, perm-packed bf16 stores
    // out col c = wn + jj*16 + l16 -> storage pos = (c&64) + l16*4 + ((c>>4)&3)
    int pb = ((wave & 2) << 5) + (l16 << 2) + ((wave & 1) << 1);
    float b0 = bias[wn + l16], b1 = bias[wn + 16 + l16];
#pragma unroll
    for (int i = 0; i < 4; ++i)
#pragma unroll
        for (int reg = 0; reg < 4; ++reg) {
            int grow = row0 + i * 16 + quad * 4 + reg;
            if (grow >= NN) continue;
            unsigned u = (unsigned)f2bf(fmaxf(acc[i][0][reg] + b0, 0.f))
                       | ((unsigned)f2bf(fmaxf(acc[i][1][reg] + b1, 0.f)) << 16);
            *(unsigned*)(hout + (size_t)grow * HID + pb) = u;
        }
}

// ---------------- global mean pool: sorted-batch register accumulation (position-wise)
__global__ __launch_bounds__(256) void pool_kernel(const unsigned short* __restrict__ habf,
                                                   const int* __restrict__ batch,
                                                   float* __restrict__ psum,
                                                   float* __restrict__ pcnt) {
    int tid = threadIdx.x;
    int f = tid & 127;
    int sub = tid >> 7;
    int base = blockIdx.x * PCHUNK;
    float acc = 0.f, cnt = 0.f;
    int gcur = -1;
    for (int it = 0; it < PCHUNK / 2; ++it) {
        int node = base + it * 2 + sub;
        if (node >= NN) break;
        int g = batch[node];
        if (g != gcur) {
            if (gcur >= 0) {
                atomicAdd(&psum[gcur * HID + f], acc);
                if (f == 0) atomicAdd(&pcnt[gcur], cnt);
            }
            gcur = g; acc = 0.f; cnt = 0.f;
        }
        acc += bf2f(habf[(size_t)node * HID + f]);
        cnt += 1.f;
    }
    if (gcur >= 0) {
        atomicAdd(&psum[gcur * HID + f], acc);
        if (f == 0) atomicAdd(&pcnt[gcur], cnt);
    }
}

// ---------------- head (unpermutes psum)
__global__ void head_kernel(const float* __restrict__ psum, const float* __restrict__ pcnt,
                            const float* __restrict__ g2, const float* __restrict__ b2,
                            const float* __restrict__ m2, const float* __restrict__ v2,
                            const float* __restrict__ fc1w, const float* __restrict__ fc1b,
                            const float* __restrict__ fc2w, const float* __restrict__ fc2b,
                            float* __restrict__ out) {
    __shared__ float v[HID];
    __shared__ float u[HID];
    __shared__ float lg[CLASSES];
    int j = threadIdx.x;
    int pj = permf(j);
    float acc = 0.f;
    for (int g = 0; g < GRAPHS; ++g) {
        float val = psum[g * HID + pj] / fmaxf(pcnt[g], 1.0f);
        val = (val - m2[j]) * rsqrtf(v2[j] + EPSV) * g2[j] + b2[j];
        acc += val;
    }
    v[j] = fmaxf(acc / (float)GRAPHS, 0.f);
    __syncthreads();
    float s = fc1b[j];
    for (int k = 0; k < HID; ++k) s += v[k] * fc1w[k * HID + j];
    u[j] = fmaxf(s, 0.f);
    __syncthreads();
    if (j < CLASSES) {
        float t = fc2b[j];
        for (int k = 0; k < HID; ++k) t += u[k] * fc2w[k * CLASSES + j];
        lg[j] = t;
    }
    __syncthreads();
    if (j < CLASSES) {
        float mx = lg[0];
        for (int c = 1; c < CLASSES; ++c) mx = fmaxf(mx, lg[c]);
        float se = 0.f;
        for (int c = 0; c < CLASSES; ++c) se += expf(lg[c] - mx);
        out[j] = lg[j] - mx - logf(se);
    }
}

extern "C" void kernel_launch(void* const* d_in, const int* in_sizes, int n_in,
                              void* d_out, int out_size, void* d_ws, size_t ws_size,
                              hipStream_t stream) {
    const float* x     = (const float*)d_in[0];
    const int*   ei    = (const int*)d_in[1];
    const int*   ea    = (const int*)d_in[2];
    const int*   batch = (const int*)d_in[3];
    const float* bn1g  = (const float*)d_in[4];
    const float* bn1b  = (const float*)d_in[5];
    const float* bn1m  = (const float*)d_in[6];
    const float* bn1v  = (const float*)d_in[7];
    const float* basis = (const float*)d_in[8];
    const float* comp  = (const float*)d_in[9];
    const float* root  = (const float*)d_in[10];
    const float* bias  = (const float*)d_in[11];
    const float* bn2g  = (const float*)d_in[12];
    const float* bn2b  = (const float*)d_in[13];
    const float* bn2m  = (const float*)d_in[14];
    const float* bn2v  = (const float*)d_in[15];
    const float* fc1w  = (const float*)d_in[16];
    const float* fc1b  = (const float*)d_in[17];
    const float* fc2w  = (const float*)d_in[18];
    const float* fc2b  = (const float*)d_in[19];

    float* ws = (float*)d_ws;
    size_t off = 0;
    unsigned short* wT  = (unsigned short*)(ws + off); off += (size_t)LAYERS * NOUT * HID / 2;
    unsigned short* hb0 = (unsigned short*)(ws + off); off += (size_t)NN * HID / 2;
    unsigned short* hb1 = (unsigned short*)(ws + off); off += (size_t)NN * HID / 2;
    float* deg    = ws + off; off += (size_t)NSEG;
    float* psum   = ws + off; off += (size_t)GRAPHS * HID + GRAPHS;
    float* pcnt   = psum + GRAPHS * HID;
    int* rowptr2  = (int*)(ws + off); off += (size_t)NSEG + 1;
    int* fillcnt2 = (int*)(ws + off); off += (size_t)NSEG;
    int* bsum     = (int*)(ws + off); off += (size_t)SCAN_NBLK2;
    int* epk2     = (int*)(ws + off); off += (size_t)NE;
    if (ws_size < off * sizeof(float)) return;

    hipMemsetAsync(psum, 0, (GRAPHS * HID + GRAPHS) * sizeof(float), stream);
    hipMemsetAsync(deg, 0, (size_t)NSEG * sizeof(float), stream);
    hipMemsetAsync(fillcnt2, 0, (size_t)NSEG * sizeof(int), stream);

    build_wcat<<<LAYERS * 64, 256, 0, stream>>>(basis, comp, root, wT);
    bn1_kernel<<<(NN * HID + 255) / 256, 256, 0, stream>>>(x, bn1g, bn1b, bn1m, bn1v, hb0);

    deg_kernel<<<(NE + 255) / 256, 256, 0, stream>>>(ei, ea, deg);
    scan_partial<<<SCAN_NBLK2, 256, 0, stream>>>(deg, rowptr2, bsum);
    scan_bsum<<<1, 512, 0, stream>>>(bsum);
    scan_add<<<(NSEG + 255) / 256, 256, 0, stream>>>(rowptr2, bsum);
    fill_kernel<<<(NE + 255) / 256, 256, 0, stream>>>(ei, ea, rowptr2, fillcnt2, epk2);

    const unsigned short* hin = hb0;
    unsigned short* hout = hb1;
    for (int l = 0; l < LAYERS; ++l) {
        rgcn_layer<<<NDBLK, 256, 0, stream>>>(hin, wT + (size_t)l * NOUT * HID,
                                              bias + (size_t)l * HID, rowptr2, epk2, deg, hout);
        const unsigned short* t = hin; hin = hout; hout = (unsigned short*)t;
    }

    pool_kernel<<<(NN + PCHUNK - 1) / PCHUNK, 256, 0, stream>>>(hin, batch, psum, pcnt);
    head_kernel<<<1, 128, 0, stream>>>(psum, pcnt, bn2g, bn2b, bn2m, bn2v,
                                       fc1w, fc1b, fc2w, fc2b, (float*)d_out);
}